// Round 3
// baseline (1653.720 us; speedup 1.0000x reference)
//
#include <hip/hip_runtime.h>
#include <stdint.h>

#define BSAMP 4096
#define NTOT  65536
#define INW   64
#define HW    512
#define DW    256
#define EMB_IN 832

typedef unsigned short ushort_t;
using bf16x8 = __attribute__((ext_vector_type(8))) short;
using f32x4  = __attribute__((ext_vector_type(4))) float;

__device__ __forceinline__ ushort_t f2bf(float f) {
    unsigned int x = __builtin_bit_cast(unsigned int, f);
    x = x + 0x7fff + ((x >> 16) & 1);   // round-to-nearest-even
    return (ushort_t)(x >> 16);
}

// async global->LDS, 16B per lane; lds base must be wave-uniform (HW scatters +lane*16)
__device__ __forceinline__ void async16(const void* g, void* l) {
    __builtin_amdgcn_global_load_lds((const __attribute__((address_space(1))) unsigned int*)g,
                                     (__attribute__((address_space(3))) unsigned int*)l,
                                     16, 0, 0);
}

// ---------------------------------------------------------------------------
// vectorized fp32 -> bf16 (4 elems/thread)
__global__ __launch_bounds__(256) void k_cvt4(const float* __restrict__ in,
                                              ushort_t* __restrict__ out, int n4) {
    int i = blockIdx.x * 256 + threadIdx.x;
    if (i >= n4) return;
    float4 v = *(const float4*)(in + (size_t)i * 4);
    uint2 o;
    o.x = (unsigned)f2bf(v.x) | ((unsigned)f2bf(v.y) << 16);
    o.y = (unsigned)f2bf(v.z) | ((unsigned)f2bf(v.w) << 16);
    *(uint2*)(out + (size_t)i * 4) = o;
}

// W_emb fp32 [832][512] -> wembT bf16 [512][832]
__global__ __launch_bounds__(256) void k_transpose(const float* __restrict__ in,
                                                   ushort_t* __restrict__ out) {
    int i = blockIdx.x * 256 + threadIdx.x;
    if (i >= HW * EMB_IN) return;
    int n = i / EMB_IN;
    int k = i - n * EMB_IN;
    out[i] = f2bf(in[k * HW + n]);
}

// wrz[g*512+h][k] = k<512 ? w_ih[(g*512+h)][k] : w_hh[(g*512+h)][k-512],  g in {r,z}
__global__ __launch_bounds__(256) void k_build_wrz(const float* __restrict__ wih,
                                                   const float* __restrict__ whh,
                                                   ushort_t* __restrict__ wrz) {
    int i = blockIdx.x * 256 + threadIdx.x;           // 1024*1024
    int row = i >> 10, k = i & 1023;
    float v = (k < 512) ? wih[row * 512 + k] : whh[row * 512 + (k - 512)];
    wrz[i] = f2bf(v);
}

// wnn[h][k] = k<512 ? w_ih[1024+h][k] : w_hh[1024+h][k-512]
__global__ __launch_bounds__(256) void k_build_wnn(const float* __restrict__ wih,
                                                   const float* __restrict__ whh,
                                                   ushort_t* __restrict__ wnn) {
    int i = blockIdx.x * 256 + threadIdx.x;           // 512*1024
    int h = i >> 10, k = i & 1023;
    float v = (k < 512) ? wih[(1024 + h) * 512 + k] : whh[(1024 + h) * 512 + (k - 512)];
    wnn[i] = f2bf(v);
}

__global__ __launch_bounds__(256) void k_sid(const int* __restrict__ starts,
                                             int* __restrict__ sid) {
    int n = blockIdx.x * 256 + threadIdx.x;
    int lo = 0, hi = BSAMP - 1;
    #pragma unroll
    for (int it = 0; it < 12; ++it) {
        int mid = (lo + hi + 1) >> 1;
        if (starts[mid] <= n) lo = mid; else hi = mid - 1;
    }
    sid[n] = lo;
}

// ht (chunk, fp32, pre-offset) -> Acat cols 512..1023 bf16
__global__ __launch_bounds__(256) void k_cvt_ht(const float* __restrict__ ht,
                                                ushort_t* __restrict__ Acat, int n128) {
    int i = blockIdx.x * 256 + threadIdx.x;           // nrows*128
    if (i >= n128) return;
    int row = i >> 7, c4 = i & 127;
    float4 v = *(const float4*)(ht + row * 512 + c4 * 4);
    ushort_t* d = Acat + (size_t)row * 1024 + 512 + c4 * 4;
    d[0] = f2bf(v.x); d[1] = f2bf(v.y); d[2] = f2bf(v.z); d[3] = f2bf(v.w);
}

// ---------------------------------------------------------------------------
// emb = relu(concat(neigh, traj[sid], dist) @ W_emb + b) -> Acat cols 0..511 (bf16)
// 128x128 tile, 4 waves (2x2) of 64x64, BK=64, K=832.
// A: LDS, T2-swizzled, TRIPLE-buffered, staged via global_load_lds.
// B: DIRECT from global (wembT, L2-resident) - bypasses LDS entirely.
// Pipeline: raw s_barrier + counted s_waitcnt vmcnt(4) - no vmcnt(0) drain in loop.
// T1: 1-D grid, XCD-chunked block swizzle (grid multiple of 8).
__global__ __launch_bounds__(256, 2) void k_emb(const ushort_t* __restrict__ neighbf,
                                                const ushort_t* __restrict__ trajbf,
                                                const ushort_t* __restrict__ distbf,
                                                const ushort_t* __restrict__ wembT,
                                                const float* __restrict__ bemb,
                                                const int* __restrict__ sid,
                                                ushort_t* __restrict__ Acat,
                                                int base) {
    __shared__ short As[3][128 * 64];                // 48 KiB

    const int tid = threadIdx.x;
    const int b = blockIdx.x;
    const int total = gridDim.x;                     // 4*nrb, multiple of 8
    const int lg = (b & 7) * (total >> 3) + (b >> 3);
    const int cb = lg & 3, rb = lg >> 2;
    const int lrow0 = rb * 128;
    const int row0g = base + lrow0;
    const int wave = tid >> 6, lane = tid & 63;
    const int wm = wave & 1, wn = wave >> 1;
    const int quad = lane >> 4, l15 = lane & 15;
    const int mb = wm * 64, nb = wn * 64;
    const int srow = lane >> 3, sc8 = lane & 7;
    const int swz = (l15 & 7) << 3;                  // read-side XOR (shorts)

    f32x4 acc[4][4];
    #pragma unroll
    for (int i = 0; i < 4; ++i)
        #pragma unroll
        for (int j = 0; j < 4; ++j) acc[i][j] = (f32x4){0.f, 0.f, 0.f, 0.f};

    // per-lane source pointers, hoisted (stage() is then exactly 4 async16)
    const ushort_t* nptr[4];
    const ushort_t* tptr[4];
    const ushort_t* dptr[4];
    #pragma unroll
    for (int p = 0; p < 4; ++p) {
        int row = p * 32 + wave * 8 + srow;
        int sw8 = (sc8 ^ srow) * 8;
        nptr[p] = neighbf + (size_t)(row0g + row) * 64 + sw8;
        tptr[p] = trajbf + (size_t)sid[row0g + row] * HW + sw8;
        dptr[p] = distbf + (size_t)(row0g + row) * 256 + sw8;
    }
    // B-fragment global bases (direct loads): col = cb*128 + nb + j*16 + l15
    const ushort_t* bptr[4];
    #pragma unroll
    for (int j = 0; j < 4; ++j)
        bptr[j] = wembT + (size_t)(cb * 128 + nb + j * 16 + l15) * EMB_IN + quad * 8;

    auto stageA = [&](int kk, int buf) {
        #pragma unroll
        for (int p = 0; p < 4; ++p) {
            const ushort_t* src;
            if (kk == 0)       src = nptr[p];
            else if (kk <= 8)  src = tptr[p] + (kk - 1) * 64;
            else               src = dptr[p] + (kk - 9) * 64;
            async16(src, &As[buf][p * 2048 + wave * 512]);
        }
    };

    auto compute = [&](int kk, int buf) {
        __builtin_amdgcn_s_setprio(1);
        #pragma unroll
        for (int ks = 0; ks < 2; ++ks) {
            const int kb = (ks * 32 + quad * 8) ^ swz;   // LDS (swizzled)
            const int kg = kk * 64 + ks * 32;            // global
            bf16x8 af[4], bfr[4];
            #pragma unroll
            for (int i = 0; i < 4; ++i)
                af[i] = *(const bf16x8*)(&As[buf][(mb + i * 16 + l15) * 64 + kb]);
            #pragma unroll
            for (int j = 0; j < 4; ++j)
                bfr[j] = *(const bf16x8*)(bptr[j] + kg);
            #pragma unroll
            for (int i = 0; i < 4; ++i)
                #pragma unroll
                for (int j = 0; j < 4; ++j)
                    acc[i][j] = __builtin_amdgcn_mfma_f32_16x16x32_bf16(af[i], bfr[j], acc[i][j], 0, 0, 0);
        }
        __builtin_amdgcn_s_setprio(0);
    };

    stageA(0, 0);
    int buf = 0;
    for (int kk = 0; kk < 13; ++kk) {
        int nbuf = buf + 1; if (nbuf == 3) nbuf = 0;
        if (kk < 12) {
            stageA(kk + 1, nbuf);
            asm volatile("s_waitcnt vmcnt(4)" ::: "memory");
        } else {
            asm volatile("s_waitcnt vmcnt(0)" ::: "memory");
        }
        __builtin_amdgcn_s_barrier();
        compute(kk, buf);
        buf = nbuf;
    }

    // epilogue: bias + relu -> Acat cols 0..511 (stride 1024)
    #pragma unroll
    for (int j = 0; j < 4; ++j) {
        int gn = cb * 128 + nb + j * 16 + l15;
        float bias = bemb[gn];
        #pragma unroll
        for (int i = 0; i < 4; ++i) {
            int lm0 = lrow0 + mb + i * 16 + quad * 4;
            #pragma unroll
            for (int r = 0; r < 4; ++r) {
                float v = acc[i][j][r] + bias;
                v = v > 0.f ? v : 0.f;
                Acat[(size_t)(lm0 + r) * 1024 + gn] = f2bf(v);
            }
        }
    }
}

// ---------------------------------------------------------------------------
// fused GRU: block = 128 rows x 64 h-cols; waves 2x2, wave = 64x32x3gates.
// A (Acat): LDS, T2-swizzled, TRIPLE-buffered (48 KiB), counted-vmcnt pipeline.
// B (weights): DIRECT from global - wrz/wnn are L2-resident, frag loads are
// perfectly line-coalesced (16 full 64B lines per instruction).
__global__ __launch_bounds__(256, 2) void k_gru(const ushort_t* __restrict__ Acat,
                                                const float* __restrict__ ht,
                                                const ushort_t* __restrict__ wrz,
                                                const ushort_t* __restrict__ wnn,
                                                const float* __restrict__ bih,
                                                const float* __restrict__ bhh,
                                                float* __restrict__ out,
                                                int base) {
    __shared__ short As[3][128 * 64];                // 48 KiB

    const int tid = threadIdx.x;
    const int b = blockIdx.x;
    const int total = gridDim.x;                     // 8*nrb, multiple of 8
    const int lg = (b & 7) * (total >> 3) + (b >> 3);
    const int hb = lg & 7, rb = lg >> 3;
    const int lrow0 = rb * 128;
    const int row0g = base + lrow0;
    const int h0 = hb * 64;
    const int wave = tid >> 6, lane = tid & 63;
    const int wm = wave & 1, wn = wave >> 1;
    const int quad = lane >> 4, l15 = lane & 15;
    const int mb = wm * 64, nb = wn * 32;
    const int srow = lane >> 3, sc8 = lane & 7;
    const int swz = (l15 & 7) << 3;                  // read-side XOR (shorts)

    f32x4 accR[4][2], accZ[4][2], accNI[4][2], accNH[4][2];
    #pragma unroll
    for (int i = 0; i < 4; ++i)
        #pragma unroll
        for (int j = 0; j < 2; ++j) {
            accR[i][j] = (f32x4){0.f, 0.f, 0.f, 0.f};
            accZ[i][j] = (f32x4){0.f, 0.f, 0.f, 0.f};
            accNI[i][j] = (f32x4){0.f, 0.f, 0.f, 0.f};
            accNH[i][j] = (f32x4){0.f, 0.f, 0.f, 0.f};
        }

    // A staging pointers (per-lane, hoisted)
    const ushort_t* aptr[4];
    #pragma unroll
    for (int p = 0; p < 4; ++p) {
        int row = p * 32 + wave * 8 + srow;
        aptr[p] = Acat + (size_t)(lrow0 + row) * 1024 + (sc8 ^ srow) * 8;
    }
    // B fragment bases (direct): per gate, cols nb+l15 and nb+16+l15
    const ushort_t* Wr = wrz + (size_t)h0 * 1024;
    const ushort_t* Wz = wrz + (size_t)(512 + h0) * 1024;
    const ushort_t* Wn = wnn + (size_t)h0 * 1024;
    const ushort_t* br_p0 = Wr + (size_t)(nb + l15) * 1024 + quad * 8;
    const ushort_t* br_p1 = Wr + (size_t)(nb + 16 + l15) * 1024 + quad * 8;
    const ushort_t* bz_p0 = Wz + (size_t)(nb + l15) * 1024 + quad * 8;
    const ushort_t* bz_p1 = Wz + (size_t)(nb + 16 + l15) * 1024 + quad * 8;
    const ushort_t* bn_p0 = Wn + (size_t)(nb + l15) * 1024 + quad * 8;
    const ushort_t* bn_p1 = Wn + (size_t)(nb + 16 + l15) * 1024 + quad * 8;

    auto stageA = [&](int kk, int buf) {
        #pragma unroll
        for (int p = 0; p < 4; ++p)
            async16(aptr[p] + kk * 64, &As[buf][p * 2048 + wave * 512]);
    };

    auto compute = [&](int kk, int buf, f32x4 (&accN)[4][2]) {
        __builtin_amdgcn_s_setprio(1);
        #pragma unroll
        for (int ks = 0; ks < 2; ++ks) {
            const int kb = (ks * 32 + quad * 8) ^ swz;   // LDS (swizzled)
            const int kg = kk * 64 + ks * 32;            // global
            bf16x8 af[4];
            #pragma unroll
            for (int i = 0; i < 4; ++i)
                af[i] = *(const bf16x8*)(&As[buf][(mb + i * 16 + l15) * 64 + kb]);

            bf16x8 br0 = *(const bf16x8*)(br_p0 + kg);
            bf16x8 br1 = *(const bf16x8*)(br_p1 + kg);
            #pragma unroll
            for (int i = 0; i < 4; ++i) {
                accR[i][0] = __builtin_amdgcn_mfma_f32_16x16x32_bf16(af[i], br0, accR[i][0], 0, 0, 0);
                accR[i][1] = __builtin_amdgcn_mfma_f32_16x16x32_bf16(af[i], br1, accR[i][1], 0, 0, 0);
            }
            bf16x8 bz0 = *(const bf16x8*)(bz_p0 + kg);
            bf16x8 bz1 = *(const bf16x8*)(bz_p1 + kg);
            #pragma unroll
            for (int i = 0; i < 4; ++i) {
                accZ[i][0] = __builtin_amdgcn_mfma_f32_16x16x32_bf16(af[i], bz0, accZ[i][0], 0, 0, 0);
                accZ[i][1] = __builtin_amdgcn_mfma_f32_16x16x32_bf16(af[i], bz1, accZ[i][1], 0, 0, 0);
            }
            bf16x8 bn0 = *(const bf16x8*)(bn_p0 + kg);
            bf16x8 bn1 = *(const bf16x8*)(bn_p1 + kg);
            #pragma unroll
            for (int i = 0; i < 4; ++i) {
                accN[i][0] = __builtin_amdgcn_mfma_f32_16x16x32_bf16(af[i], bn0, accN[i][0], 0, 0, 0);
                accN[i][1] = __builtin_amdgcn_mfma_f32_16x16x32_bf16(af[i], bn1, accN[i][1], 0, 0, 0);
            }
        }
        __builtin_amdgcn_s_setprio(0);
    };

    stageA(0, 0);
    int buf = 0;
    for (int kk = 0; kk < 16; ++kk) {
        int nbuf = buf + 1; if (nbuf == 3) nbuf = 0;
        if (kk < 15) {
            stageA(kk + 1, nbuf);
            asm volatile("s_waitcnt vmcnt(4)" ::: "memory");
        } else {
            asm volatile("s_waitcnt vmcnt(0)" ::: "memory");
        }
        __builtin_amdgcn_s_barrier();
        if (kk < 8) compute(kk, buf, accNI);
        else        compute(kk, buf, accNH);
        buf = nbuf;
    }

    // epilogue
    #pragma unroll
    for (int j = 0; j < 2; ++j) {
        int gn = h0 + nb + j * 16 + l15;
        float br = bih[gn] + bhh[gn];
        float bz = bih[gn + 512] + bhh[gn + 512];
        float bin = bih[gn + 1024], bhn = bhh[gn + 1024];
        #pragma unroll
        for (int i = 0; i < 4; ++i) {
            int gm0 = row0g + mb + i * 16 + quad * 4;
            #pragma unroll
            for (int r = 0; r < 4; ++r) {
                int gm = gm0 + r;
                float rg = 1.f / (1.f + __expf(-(accR[i][j][r] + br)));
                float zg = 1.f / (1.f + __expf(-(accZ[i][j][r] + bz)));
                float ng = tanhf(accNI[i][j][r] + bin + rg * (accNH[i][j][r] + bhn));
                float hp = ht[(size_t)gm * HW + gn];
                out[(size_t)gm * HW + gn] = (1.f - zg) * ng + zg * hp;
            }
        }
    }
}

// ---------------------------------------------------------------------------
extern "C" void kernel_launch(void* const* d_in, const int* in_sizes, int n_in,
                              void* d_out, int out_size, void* d_ws, size_t ws_size,
                              hipStream_t stream) {
    const float* traj   = (const float*)d_in[0];
    const float* neigh  = (const float*)d_in[1];
    const float* dist   = (const float*)d_in[2];
    const float* ht     = (const float*)d_in[3];
    const float* W_emb  = (const float*)d_in[4];
    const float* b_emb  = (const float*)d_in[5];
    const float* w_ih   = (const float*)d_in[6];
    const float* w_hh   = (const float*)d_in[7];
    const float* b_ih   = (const float*)d_in[8];
    const float* b_hh   = (const float*)d_in[9];
    const int*   starts = (const int*)d_in[10];

    // ws layout (all 16B-aligned)
    char* ws = (char*)d_ws;
    int*      sid     = (int*)ws;                         // 262144
    ushort_t* wembT   = (ushort_t*)(ws + 262144);         // 851968
    ushort_t* wrz     = (ushort_t*)(ws + 1114112);        // 2097152
    ushort_t* wnn     = (ushort_t*)(ws + 3211264);        // 1048576
    ushort_t* trajbf  = (ushort_t*)(ws + 4259840);        // 4194304
    ushort_t* neighbf = (ushort_t*)(ws + 8454144);        // 8388608
    ushort_t* distbf  = (ushort_t*)(ws + 16842752);       // 33554432
    ushort_t* Acat    = (ushort_t*)(ws + 50397184);       // chunk_rows * 2048 B

    float* out = (float*)d_out;

    // adaptive chunk size from available workspace (deterministic per call)
    long long avail = (long long)ws_size - 50397184LL;
    int chunk_rows = (int)(avail / 2048);
    chunk_rows &= ~255;                     // multiple of 256 so grids are %8==0
    if (chunk_rows > NTOT) chunk_rows = NTOT;
    if (chunk_rows < 256) chunk_rows = 256;

    k_sid<<<dim3(NTOT / 256), dim3(256), 0, stream>>>(starts, sid);
    k_cvt4<<<dim3(BSAMP * HW / 1024), dim3(256), 0, stream>>>(traj, trajbf, BSAMP * HW / 4);
    k_cvt4<<<dim3(NTOT * INW / 1024), dim3(256), 0, stream>>>(neigh, neighbf, NTOT * INW / 4);
    k_cvt4<<<dim3(NTOT * DW / 1024), dim3(256), 0, stream>>>(dist, distbf, NTOT * DW / 4);
    k_transpose<<<dim3((HW * EMB_IN + 255) / 256), dim3(256), 0, stream>>>(W_emb, wembT);
    k_build_wrz<<<dim3(1024 * 1024 / 256), dim3(256), 0, stream>>>(w_ih, w_hh, wrz);
    k_build_wnn<<<dim3(512 * 1024 / 256), dim3(256), 0, stream>>>(w_ih, w_hh, wnn);

    for (int base = 0; base < NTOT; base += chunk_rows) {
        int rows = NTOT - base;
        if (rows > chunk_rows) rows = chunk_rows;
        int n128 = rows * 128;
        k_cvt_ht<<<dim3((n128 + 255) / 256), dim3(256), 0, stream>>>(ht + (size_t)base * HW, Acat, n128);
        k_emb<<<dim3(4 * (rows / 128)), dim3(256), 0, stream>>>(neighbf, trajbf, distbf, wembT,
                                                                b_emb, sid, Acat, base);
        k_gru<<<dim3(8 * (rows / 128)), dim3(256), 0, stream>>>(Acat, ht, wrz, wnn,
                                                                b_ih, b_hh, out, base);
    }
}

// Round 4
// 1346.825 us; speedup vs baseline: 1.2279x; 1.2279x over previous
//
#include <hip/hip_runtime.h>
#include <stdint.h>

#define BSAMP 4096
#define NTOT  65536
#define INW   64
#define HW    512
#define DW    256
#define EMB_IN 832

typedef unsigned short ushort_t;
using bf16x8 = __attribute__((ext_vector_type(8))) short;
using f32x4  = __attribute__((ext_vector_type(4))) float;

__device__ __forceinline__ ushort_t f2bf(float f) {
    unsigned int x = __builtin_bit_cast(unsigned int, f);
    x = x + 0x7fff + ((x >> 16) & 1);   // round-to-nearest-even
    return (ushort_t)(x >> 16);
}

// async global->LDS, 16B per lane; lds base must be wave-uniform (HW scatters +lane*16)
__device__ __forceinline__ void async16(const void* g, void* l) {
    __builtin_amdgcn_global_load_lds((const __attribute__((address_space(1))) unsigned int*)g,
                                     (__attribute__((address_space(3))) unsigned int*)l,
                                     16, 0, 0);
}

// ---------------------------------------------------------------------------
// vectorized fp32 -> bf16 (4 elems/thread)
__global__ __launch_bounds__(256) void k_cvt4(const float* __restrict__ in,
                                              ushort_t* __restrict__ out, int n4) {
    int i = blockIdx.x * 256 + threadIdx.x;
    if (i >= n4) return;
    float4 v = *(const float4*)(in + (size_t)i * 4);
    uint2 o;
    o.x = (unsigned)f2bf(v.x) | ((unsigned)f2bf(v.y) << 16);
    o.y = (unsigned)f2bf(v.z) | ((unsigned)f2bf(v.w) << 16);
    *(uint2*)(out + (size_t)i * 4) = o;
}

// W_emb fp32 [832][512] -> wembT bf16 [512][832]
__global__ __launch_bounds__(256) void k_transpose(const float* __restrict__ in,
                                                   ushort_t* __restrict__ out) {
    int i = blockIdx.x * 256 + threadIdx.x;
    if (i >= HW * EMB_IN) return;
    int n = i / EMB_IN;
    int k = i - n * EMB_IN;
    out[i] = f2bf(in[k * HW + n]);
}

// wrz[g*512+h][k] = k<512 ? w_ih[(g*512+h)][k] : w_hh[(g*512+h)][k-512],  g in {r,z}
__global__ __launch_bounds__(256) void k_build_wrz(const float* __restrict__ wih,
                                                   const float* __restrict__ whh,
                                                   ushort_t* __restrict__ wrz) {
    int i = blockIdx.x * 256 + threadIdx.x;           // 1024*1024
    int row = i >> 10, k = i & 1023;
    float v = (k < 512) ? wih[row * 512 + k] : whh[row * 512 + (k - 512)];
    wrz[i] = f2bf(v);
}

// wnn[h][k] = k<512 ? w_ih[1024+h][k] : w_hh[1024+h][k-512]
__global__ __launch_bounds__(256) void k_build_wnn(const float* __restrict__ wih,
                                                   const float* __restrict__ whh,
                                                   ushort_t* __restrict__ wnn) {
    int i = blockIdx.x * 256 + threadIdx.x;           // 512*1024
    int h = i >> 10, k = i & 1023;
    float v = (k < 512) ? wih[(1024 + h) * 512 + k] : whh[(1024 + h) * 512 + (k - 512)];
    wnn[i] = f2bf(v);
}

__global__ __launch_bounds__(256) void k_sid(const int* __restrict__ starts,
                                             int* __restrict__ sid) {
    int n = blockIdx.x * 256 + threadIdx.x;
    int lo = 0, hi = BSAMP - 1;
    #pragma unroll
    for (int it = 0; it < 12; ++it) {
        int mid = (lo + hi + 1) >> 1;
        if (starts[mid] <= n) lo = mid; else hi = mid - 1;
    }
    sid[n] = lo;
}

// ht (chunk, fp32, pre-offset) -> Acat cols 512..1023 bf16
__global__ __launch_bounds__(256) void k_cvt_ht(const float* __restrict__ ht,
                                                ushort_t* __restrict__ Acat, int n128) {
    int i = blockIdx.x * 256 + threadIdx.x;           // nrows*128
    if (i >= n128) return;
    int row = i >> 7, c4 = i & 127;
    float4 v = *(const float4*)(ht + row * 512 + c4 * 4);
    ushort_t* d = Acat + (size_t)row * 1024 + 512 + c4 * 4;
    d[0] = f2bf(v.x); d[1] = f2bf(v.y); d[2] = f2bf(v.z); d[3] = f2bf(v.w);
}

// ---------------------------------------------------------------------------
// emb = relu(concat(neigh, traj[sid], dist) @ W_emb + b) -> Acat cols 0..511 (bf16)
// 128x128 tile, 4 waves (2x2) of 64x64, BK=64, K=832.
// T2: LDS XOR-swizzle on the per-lane GLOBAL source column + matching read XOR.
// T4: counted vmcnt pipeline - per tile {stage(k+1); vmcnt(8); bar; compute(k); bar}.
//     No vmcnt(0) drain in the loop; wait covers stage(k) issued a full tile ago.
// T1: 1-D grid, XCD-chunked block swizzle (grid multiple of 8). T5: setprio.
__global__ __launch_bounds__(256, 2) void k_emb(const ushort_t* __restrict__ neighbf,
                                                const ushort_t* __restrict__ trajbf,
                                                const ushort_t* __restrict__ distbf,
                                                const ushort_t* __restrict__ wembT,
                                                const float* __restrict__ bemb,
                                                const int* __restrict__ sid,
                                                ushort_t* __restrict__ Acat,
                                                int base) {
    __shared__ short As[2][128 * 64];                // 32 KiB
    __shared__ short Bs[2][128 * 64];                // 32 KiB

    const int tid = threadIdx.x;
    const int b = blockIdx.x;
    const int total = gridDim.x;                     // 4*nrb, multiple of 8
    const int lg = (b & 7) * (total >> 3) + (b >> 3);
    const int cb = lg & 3, rb = lg >> 2;
    const int lrow0 = rb * 128;
    const int row0g = base + lrow0;
    const int wave = tid >> 6, lane = tid & 63;
    const int wm = wave & 1, wn = wave >> 1;
    const int quad = lane >> 4, l15 = lane & 15;
    const int mb = wm * 64, nb = wn * 64;
    const int srow = lane >> 3, sc8 = lane & 7;
    const int swz = (l15 & 7) << 3;                  // read-side XOR (shorts)

    f32x4 acc[4][4];
    #pragma unroll
    for (int i = 0; i < 4; ++i)
        #pragma unroll
        for (int j = 0; j < 4; ++j) acc[i][j] = (f32x4){0.f, 0.f, 0.f, 0.f};

    // hoisted per-lane source pointers (stage() is then pure async16 issues)
    const ushort_t* nptr[4];
    const ushort_t* tptr[4];
    const ushort_t* dptr[4];
    const ushort_t* wptr[4];
    #pragma unroll
    for (int p = 0; p < 4; ++p) {
        int row = p * 32 + wave * 8 + srow;
        int sw8 = (sc8 ^ srow) * 8;
        nptr[p] = neighbf + (size_t)(row0g + row) * 64 + sw8;
        tptr[p] = trajbf + (size_t)sid[row0g + row] * HW + sw8;
        dptr[p] = distbf + (size_t)(row0g + row) * 256 + sw8;
        wptr[p] = wembT + (size_t)(cb * 128 + row) * EMB_IN + sw8;
    }

    auto stage = [&](int kk, int buf) {
        #pragma unroll
        for (int p = 0; p < 4; ++p)
            async16(wptr[p] + kk * 64, &Bs[buf][p * 2048 + wave * 512]);
        #pragma unroll
        for (int p = 0; p < 4; ++p) {
            const ushort_t* src;
            if (kk == 0)       src = nptr[p];
            else if (kk <= 8)  src = tptr[p] + (kk - 1) * 64;
            else               src = dptr[p] + (kk - 9) * 64;
            async16(src, &As[buf][p * 2048 + wave * 512]);
        }
    };

    auto compute = [&](int buf) {
        __builtin_amdgcn_s_setprio(1);
        #pragma unroll
        for (int ks = 0; ks < 2; ++ks) {
            const int kb = (ks * 32 + quad * 8) ^ swz;
            bf16x8 af[4], bfr[4];
            #pragma unroll
            for (int i = 0; i < 4; ++i)
                af[i] = *(const bf16x8*)(&As[buf][(mb + i * 16 + l15) * 64 + kb]);
            #pragma unroll
            for (int j = 0; j < 4; ++j)
                bfr[j] = *(const bf16x8*)(&Bs[buf][(nb + j * 16 + l15) * 64 + kb]);
            #pragma unroll
            for (int i = 0; i < 4; ++i)
                #pragma unroll
                for (int j = 0; j < 4; ++j)
                    acc[i][j] = __builtin_amdgcn_mfma_f32_16x16x32_bf16(af[i], bfr[j], acc[i][j], 0, 0, 0);
        }
        __builtin_amdgcn_s_setprio(0);
    };

    stage(0, 0);
    for (int kk = 0; kk < 13; ++kk) {
        int buf = kk & 1;
        if (kk < 12) {
            stage(kk + 1, buf ^ 1);
            asm volatile("s_waitcnt vmcnt(8)" ::: "memory");   // stage(kk) done; 8 newest fly
        } else {
            asm volatile("s_waitcnt vmcnt(0)" ::: "memory");
        }
        __builtin_amdgcn_s_barrier();        // all waves' stage(kk) visible
        compute(buf);
        __builtin_amdgcn_s_barrier();        // close readers of buf before it is re-staged
    }

    // epilogue: bias + relu -> Acat cols 0..511 (stride 1024)
    #pragma unroll
    for (int j = 0; j < 4; ++j) {
        int gn = cb * 128 + nb + j * 16 + l15;
        float bias = bemb[gn];
        #pragma unroll
        for (int i = 0; i < 4; ++i) {
            int lm0 = lrow0 + mb + i * 16 + quad * 4;
            #pragma unroll
            for (int r = 0; r < 4; ++r) {
                float v = acc[i][j][r] + bias;
                v = v > 0.f ? v : 0.f;
                Acat[(size_t)(lm0 + r) * 1024 + gn] = f2bf(v);
            }
        }
    }
}

// ---------------------------------------------------------------------------
// fused GRU: block = 128 rows x 64 h-cols; waves 2x2, wave = 64x32x3gates.
// A (Acat) + B (weights) LDS-staged (B direct-from-global FAILED in R3: L2 does
// not retain weights under streaming eviction -> 3.4 GB HBM, MfmaUtil 6.7%).
// T4 counted-vmcnt pipeline: {stage(k+1); vmcnt(10); bar; compute(k); bar}.
__global__ __launch_bounds__(256, 2) void k_gru(const ushort_t* __restrict__ Acat,
                                                const float* __restrict__ ht,
                                                const ushort_t* __restrict__ wrz,
                                                const ushort_t* __restrict__ wnn,
                                                const float* __restrict__ bih,
                                                const float* __restrict__ bhh,
                                                float* __restrict__ out,
                                                int base) {
    __shared__ short As[2][128 * 64];                // 32 KiB
    __shared__ short Bs[2][3 * 64 * 64];             // 48 KiB  (80 KiB total -> 2 blk/CU)

    const int tid = threadIdx.x;
    const int b = blockIdx.x;
    const int total = gridDim.x;                     // 8*nrb, multiple of 8
    const int lg = (b & 7) * (total >> 3) + (b >> 3);
    const int hb = lg & 7, rb = lg >> 3;
    const int lrow0 = rb * 128;
    const int row0g = base + lrow0;
    const int h0 = hb * 64;
    const int wave = tid >> 6, lane = tid & 63;
    const int wm = wave & 1, wn = wave >> 1;
    const int quad = lane >> 4, l15 = lane & 15;
    const int mb = wm * 64, nb = wn * 32;
    const int srow = lane >> 3, sc8 = lane & 7;
    const int swz = (l15 & 7) << 3;                  // read-side XOR (shorts)

    f32x4 accR[4][2], accZ[4][2], accNI[4][2], accNH[4][2];
    #pragma unroll
    for (int i = 0; i < 4; ++i)
        #pragma unroll
        for (int j = 0; j < 2; ++j) {
            accR[i][j] = (f32x4){0.f, 0.f, 0.f, 0.f};
            accZ[i][j] = (f32x4){0.f, 0.f, 0.f, 0.f};
            accNI[i][j] = (f32x4){0.f, 0.f, 0.f, 0.f};
            accNH[i][j] = (f32x4){0.f, 0.f, 0.f, 0.f};
        }

    // hoisted per-lane staging pointers
    const ushort_t* aptr[4];
    const ushort_t* rzn[3][2];                       // [gate][p]
    {
        const ushort_t* Wr = wrz + (size_t)h0 * 1024;
        const ushort_t* Wz = wrz + (size_t)(512 + h0) * 1024;
        const ushort_t* Wn = wnn + (size_t)h0 * 1024;
        #pragma unroll
        for (int p = 0; p < 4; ++p) {
            int row = p * 32 + wave * 8 + srow;
            aptr[p] = Acat + (size_t)(lrow0 + row) * 1024 + (sc8 ^ srow) * 8;
        }
        #pragma unroll
        for (int p = 0; p < 2; ++p) {
            int row = p * 32 + wave * 8 + srow;
            int goff = row * 1024 + (sc8 ^ srow) * 8;
            rzn[0][p] = Wr + goff;
            rzn[1][p] = Wz + goff;
            rzn[2][p] = Wn + goff;
        }
    }

    auto stage = [&](int kk, int buf) {
        #pragma unroll
        for (int p = 0; p < 4; ++p)
            async16(aptr[p] + kk * 64, &As[buf][p * 2048 + wave * 512]);
        #pragma unroll
        for (int p = 0; p < 2; ++p) {
            int loff = p * 2048 + wave * 512;
            async16(rzn[0][p] + kk * 64, &Bs[buf][loff]);
            async16(rzn[1][p] + kk * 64, &Bs[buf][4096 + loff]);
            async16(rzn[2][p] + kk * 64, &Bs[buf][8192 + loff]);
        }
    };

    auto compute = [&](int buf, f32x4 (&accN)[4][2]) {
        __builtin_amdgcn_s_setprio(1);
        #pragma unroll
        for (int ks = 0; ks < 2; ++ks) {
            const int kb = (ks * 32 + quad * 8) ^ swz;
            bf16x8 af[4];
            #pragma unroll
            for (int i = 0; i < 4; ++i)
                af[i] = *(const bf16x8*)(&As[buf][(mb + i * 16 + l15) * 64 + kb]);

            bf16x8 br0 = *(const bf16x8*)(&Bs[buf][(nb + l15) * 64 + kb]);
            bf16x8 br1 = *(const bf16x8*)(&Bs[buf][(nb + 16 + l15) * 64 + kb]);
            #pragma unroll
            for (int i = 0; i < 4; ++i) {
                accR[i][0] = __builtin_amdgcn_mfma_f32_16x16x32_bf16(af[i], br0, accR[i][0], 0, 0, 0);
                accR[i][1] = __builtin_amdgcn_mfma_f32_16x16x32_bf16(af[i], br1, accR[i][1], 0, 0, 0);
            }
            bf16x8 bz0 = *(const bf16x8*)(&Bs[buf][4096 + (nb + l15) * 64 + kb]);
            bf16x8 bz1 = *(const bf16x8*)(&Bs[buf][4096 + (nb + 16 + l15) * 64 + kb]);
            #pragma unroll
            for (int i = 0; i < 4; ++i) {
                accZ[i][0] = __builtin_amdgcn_mfma_f32_16x16x32_bf16(af[i], bz0, accZ[i][0], 0, 0, 0);
                accZ[i][1] = __builtin_amdgcn_mfma_f32_16x16x32_bf16(af[i], bz1, accZ[i][1], 0, 0, 0);
            }
            bf16x8 bn0 = *(const bf16x8*)(&Bs[buf][8192 + (nb + l15) * 64 + kb]);
            bf16x8 bn1 = *(const bf16x8*)(&Bs[buf][8192 + (nb + 16 + l15) * 64 + kb]);
            #pragma unroll
            for (int i = 0; i < 4; ++i) {
                accN[i][0] = __builtin_amdgcn_mfma_f32_16x16x32_bf16(af[i], bn0, accN[i][0], 0, 0, 0);
                accN[i][1] = __builtin_amdgcn_mfma_f32_16x16x32_bf16(af[i], bn1, accN[i][1], 0, 0, 0);
            }
        }
        __builtin_amdgcn_s_setprio(0);
    };

    stage(0, 0);
    for (int kk = 0; kk < 16; ++kk) {
        int buf = kk & 1;
        if (kk < 15) {
            stage(kk + 1, buf ^ 1);
            asm volatile("s_waitcnt vmcnt(10)" ::: "memory");  // stage(kk) done; 10 newest fly
        } else {
            asm volatile("s_waitcnt vmcnt(0)" ::: "memory");
        }
        __builtin_amdgcn_s_barrier();        // all waves' stage(kk) visible
        if (kk < 8) compute(buf, accNI);
        else        compute(buf, accNH);
        __builtin_amdgcn_s_barrier();        // close readers of buf before re-stage
    }

    // epilogue
    #pragma unroll
    for (int j = 0; j < 2; ++j) {
        int gn = h0 + nb + j * 16 + l15;
        float br = bih[gn] + bhh[gn];
        float bz = bih[gn + 512] + bhh[gn + 512];
        float bin = bih[gn + 1024], bhn = bhh[gn + 1024];
        #pragma unroll
        for (int i = 0; i < 4; ++i) {
            int gm0 = row0g + mb + i * 16 + quad * 4;
            #pragma unroll
            for (int r = 0; r < 4; ++r) {
                int gm = gm0 + r;
                float rg = 1.f / (1.f + __expf(-(accR[i][j][r] + br)));
                float zg = 1.f / (1.f + __expf(-(accZ[i][j][r] + bz)));
                float ng = tanhf(accNI[i][j][r] + bin + rg * (accNH[i][j][r] + bhn));
                float hp = ht[(size_t)gm * HW + gn];
                out[(size_t)gm * HW + gn] = (1.f - zg) * ng + zg * hp;
            }
        }
    }
}

// ---------------------------------------------------------------------------
extern "C" void kernel_launch(void* const* d_in, const int* in_sizes, int n_in,
                              void* d_out, int out_size, void* d_ws, size_t ws_size,
                              hipStream_t stream) {
    const float* traj   = (const float*)d_in[0];
    const float* neigh  = (const float*)d_in[1];
    const float* dist   = (const float*)d_in[2];
    const float* ht     = (const float*)d_in[3];
    const float* W_emb  = (const float*)d_in[4];
    const float* b_emb  = (const float*)d_in[5];
    const float* w_ih   = (const float*)d_in[6];
    const float* w_hh   = (const float*)d_in[7];
    const float* b_ih   = (const float*)d_in[8];
    const float* b_hh   = (const float*)d_in[9];
    const int*   starts = (const int*)d_in[10];

    // ws layout (all 16B-aligned)
    char* ws = (char*)d_ws;
    int*      sid     = (int*)ws;                         // 262144
    ushort_t* wembT   = (ushort_t*)(ws + 262144);         // 851968
    ushort_t* wrz     = (ushort_t*)(ws + 1114112);        // 2097152
    ushort_t* wnn     = (ushort_t*)(ws + 3211264);        // 1048576
    ushort_t* trajbf  = (ushort_t*)(ws + 4259840);        // 4194304
    ushort_t* neighbf = (ushort_t*)(ws + 8454144);        // 8388608
    ushort_t* distbf  = (ushort_t*)(ws + 16842752);       // 33554432
    ushort_t* Acat    = (ushort_t*)(ws + 50397184);       // chunk_rows * 2048 B

    float* out = (float*)d_out;

    // adaptive chunk size from available workspace (deterministic per call)
    long long avail = (long long)ws_size - 50397184LL;
    int chunk_rows = (int)(avail / 2048);
    chunk_rows &= ~255;                     // multiple of 256 so grids are %8==0
    if (chunk_rows > NTOT) chunk_rows = NTOT;
    if (chunk_rows < 256) chunk_rows = 256;

    k_sid<<<dim3(NTOT / 256), dim3(256), 0, stream>>>(starts, sid);
    k_cvt4<<<dim3(BSAMP * HW / 1024), dim3(256), 0, stream>>>(traj, trajbf, BSAMP * HW / 4);
    k_cvt4<<<dim3(NTOT * INW / 1024), dim3(256), 0, stream>>>(neigh, neighbf, NTOT * INW / 4);
    k_cvt4<<<dim3(NTOT * DW / 1024), dim3(256), 0, stream>>>(dist, distbf, NTOT * DW / 4);
    k_transpose<<<dim3((HW * EMB_IN + 255) / 256), dim3(256), 0, stream>>>(W_emb, wembT);
    k_build_wrz<<<dim3(1024 * 1024 / 256), dim3(256), 0, stream>>>(w_ih, w_hh, wrz);
    k_build_wnn<<<dim3(512 * 1024 / 256), dim3(256), 0, stream>>>(w_ih, w_hh, wnn);

    for (int base = 0; base < NTOT; base += chunk_rows) {
        int rows = NTOT - base;
        if (rows > chunk_rows) rows = chunk_rows;
        int n128 = rows * 128;
        k_cvt_ht<<<dim3((n128 + 255) / 256), dim3(256), 0, stream>>>(ht + (size_t)base * HW, Acat, n128);
        k_emb<<<dim3(4 * (rows / 128)), dim3(256), 0, stream>>>(neighbf, trajbf, distbf, wembT,
                                                                b_emb, sid, Acat, base);
        k_gru<<<dim3(8 * (rows / 128)), dim3(256), 0, stream>>>(Acat, ht, wrz, wnn,
                                                                b_ih, b_hh, out, base);
    }
}

// Round 5
// 692.080 us; speedup vs baseline: 2.3895x; 1.9461x over previous
//
#include <hip/hip_runtime.h>
#include <stdint.h>

#define BSAMP 4096
#define NTOT  65536
#define INW   64
#define HW    512
#define DW    256
#define EMB_IN 832

typedef unsigned short ushort_t;
using bf16x8 = __attribute__((ext_vector_type(8))) short;
using f32x4  = __attribute__((ext_vector_type(4))) float;

__device__ __forceinline__ ushort_t f2bf(float f) {
    unsigned int x = __builtin_bit_cast(unsigned int, f);
    x = x + 0x7fff + ((x >> 16) & 1);   // round-to-nearest-even
    return (ushort_t)(x >> 16);
}

// async global->LDS, 16B per lane; lds base must be wave-uniform (HW scatters +lane*16)
__device__ __forceinline__ void async16(const void* g, void* l) {
    __builtin_amdgcn_global_load_lds((const __attribute__((address_space(1))) unsigned int*)g,
                                     (__attribute__((address_space(3))) unsigned int*)l,
                                     16, 0, 0);
}

// ---------------------------------------------------------------------------
// vectorized fp32 -> bf16 (4 elems/thread) - used for traj only
__global__ __launch_bounds__(256) void k_cvt4(const float* __restrict__ in,
                                              ushort_t* __restrict__ out, int n4) {
    int i = blockIdx.x * 256 + threadIdx.x;
    if (i >= n4) return;
    float4 v = *(const float4*)(in + (size_t)i * 4);
    uint2 o;
    o.x = (unsigned)f2bf(v.x) | ((unsigned)f2bf(v.y) << 16);
    o.y = (unsigned)f2bf(v.z) | ((unsigned)f2bf(v.w) << 16);
    *(uint2*)(out + (size_t)i * 4) = o;
}

// W_emb fp32 [832][512] -> wembT bf16 [512][832]
__global__ __launch_bounds__(256) void k_transpose(const float* __restrict__ in,
                                                   ushort_t* __restrict__ out) {
    int i = blockIdx.x * 256 + threadIdx.x;
    if (i >= HW * EMB_IN) return;
    int n = i / EMB_IN;
    int k = i - n * EMB_IN;
    out[i] = f2bf(in[k * HW + n]);
}

// wrz[g*512+h][k] = k<512 ? w_ih[(g*512+h)][k] : w_hh[(g*512+h)][k-512],  g in {r,z}
__global__ __launch_bounds__(256) void k_build_wrz(const float* __restrict__ wih,
                                                   const float* __restrict__ whh,
                                                   ushort_t* __restrict__ wrz) {
    int i = blockIdx.x * 256 + threadIdx.x;           // 1024*1024
    int row = i >> 10, k = i & 1023;
    float v = (k < 512) ? wih[row * 512 + k] : whh[row * 512 + (k - 512)];
    wrz[i] = f2bf(v);
}

// wnn[h][k] = k<512 ? w_ih[1024+h][k] : w_hh[1024+h][k-512]
__global__ __launch_bounds__(256) void k_build_wnn(const float* __restrict__ wih,
                                                   const float* __restrict__ whh,
                                                   ushort_t* __restrict__ wnn) {
    int i = blockIdx.x * 256 + threadIdx.x;           // 512*1024
    int h = i >> 10, k = i & 1023;
    float v = (k < 512) ? wih[(1024 + h) * 512 + k] : whh[(1024 + h) * 512 + (k - 512)];
    wnn[i] = f2bf(v);
}

__global__ __launch_bounds__(256) void k_sid(const int* __restrict__ starts,
                                             int* __restrict__ sid) {
    int n = blockIdx.x * 256 + threadIdx.x;
    int lo = 0, hi = BSAMP - 1;
    #pragma unroll
    for (int it = 0; it < 12; ++it) {
        int mid = (lo + hi + 1) >> 1;
        if (starts[mid] <= n) lo = mid; else hi = mid - 1;
    }
    sid[n] = lo;
}

// ---------------------------------------------------------------------------
// emb = relu(concat(neigh, traj[sid], dist) @ W_emb + b) -> Acat [rows][512] bf16
// 128x128 tile, 4 waves (2x2) of 64x64, BK=64, K=832.  (R2-verified structure)
// T2: LDS XOR-swizzle (async parts: pre-swizzled global source; fp32 parts:
//     swizzled ds_write). T3-min: double-buffer, stage(k+1) before compute(k),
//     ONE __syncthreads per K-step. T1: XCD-chunked swizzle. T5: setprio.
// neigh/dist are staged fp32->bf16 IN-KERNEL (k_cvt4 prep kernels removed).
__global__ __launch_bounds__(256, 2) void k_emb(const float* __restrict__ neigh,
                                                const ushort_t* __restrict__ trajbf,
                                                const float* __restrict__ dist,
                                                const ushort_t* __restrict__ wembT,
                                                const float* __restrict__ bemb,
                                                const int* __restrict__ sid,
                                                ushort_t* __restrict__ Acat,
                                                int base) {
    __shared__ short As[2][128 * 64];                // 32 KiB
    __shared__ short Bs[2][128 * 64];                // 32 KiB

    const int tid = threadIdx.x;
    const int b = blockIdx.x;
    const int total = gridDim.x;                     // 4*nrb, multiple of 8
    const int lg = (b & 7) * (total >> 3) + (b >> 3);
    const int cb = lg & 3, rb = lg >> 2;
    const int lrow0 = rb * 128;
    const int row0g = base + lrow0;
    const int wave = tid >> 6, lane = tid & 63;
    const int wm = wave & 1, wn = wave >> 1;
    const int quad = lane >> 4, l15 = lane & 15;
    const int mb = wm * 64, nb = wn * 64;
    const int srow = lane >> 3, sc8 = lane & 7;
    const int swz = (l15 & 7) << 3;                  // read-side XOR (shorts)

    f32x4 acc[4][4];
    #pragma unroll
    for (int i = 0; i < 4; ++i)
        #pragma unroll
        for (int j = 0; j < 4; ++j) acc[i][j] = (f32x4){0.f, 0.f, 0.f, 0.f};

    auto stage = [&](int kk, int buf) {
        // B tile: wembT rows [cb*128,+128), cols [kk*64,+64) - async, src-swizzled
        #pragma unroll
        for (int p = 0; p < 4; ++p) {
            int row = p * 32 + wave * 8 + srow;
            async16(wembT + (cb * 128 + row) * EMB_IN + kk * 64 + (sc8 ^ srow) * 8,
                    &Bs[buf][p * 2048 + wave * 512]);
        }
        // A tile: 128 x 64
        if (kk >= 1 && kk <= 8) {            // traj gather, bf16 async, src-swizzled
            #pragma unroll
            for (int p = 0; p < 4; ++p) {
                int row = p * 32 + wave * 8 + srow;
                async16(trajbf + (size_t)sid[row0g + row] * HW + (kk - 1) * 64 + (sc8 ^ srow) * 8,
                        &As[buf][p * 2048 + wave * 512]);
            }
        } else {                             // neigh (kk==0) / dist (kk>=9) fp32, swizzled ds_write
            const float* srcb;
            int rs;
            if (kk == 0) { srcb = neigh + (size_t)row0g * INW;                  rs = INW; }
            else         { srcb = dist + (size_t)row0g * DW + (kk - 9) * 64;    rs = DW;  }
            #pragma unroll
            for (int p = 0; p < 8; ++p) {
                int idx = p * 256 + tid;
                int row = idx >> 4, c4 = idx & 15;
                float4 v = *(const float4*)(srcb + (size_t)row * rs + c4 * 4);
                ushort_t* d = (ushort_t*)&As[buf][row * 64 + ((c4 * 4) ^ ((row & 7) << 3))];
                d[0] = f2bf(v.x); d[1] = f2bf(v.y); d[2] = f2bf(v.z); d[3] = f2bf(v.w);
            }
        }
    };

    auto compute = [&](int buf) {
        __builtin_amdgcn_s_setprio(1);
        #pragma unroll
        for (int ks = 0; ks < 2; ++ks) {
            const int kb = (ks * 32 + quad * 8) ^ swz;
            bf16x8 af[4], bfr[4];
            #pragma unroll
            for (int i = 0; i < 4; ++i)
                af[i] = *(const bf16x8*)(&As[buf][(mb + i * 16 + l15) * 64 + kb]);
            #pragma unroll
            for (int j = 0; j < 4; ++j)
                bfr[j] = *(const bf16x8*)(&Bs[buf][(nb + j * 16 + l15) * 64 + kb]);
            #pragma unroll
            for (int i = 0; i < 4; ++i)
                #pragma unroll
                for (int j = 0; j < 4; ++j)
                    acc[i][j] = __builtin_amdgcn_mfma_f32_16x16x32_bf16(af[i], bfr[j], acc[i][j], 0, 0, 0);
        }
        __builtin_amdgcn_s_setprio(0);
    };

    stage(0, 0);
    __syncthreads();
    for (int kk = 0; kk < 13; ++kk) {
        int buf = kk & 1;
        if (kk < 12) stage(kk + 1, buf ^ 1);
        compute(buf);
        __syncthreads();
    }

    // epilogue: bias + relu -> Acat [row][512]
    #pragma unroll
    for (int j = 0; j < 4; ++j) {
        int gn = cb * 128 + nb + j * 16 + l15;
        float bias = bemb[gn];
        #pragma unroll
        for (int i = 0; i < 4; ++i) {
            int lm0 = lrow0 + mb + i * 16 + quad * 4;
            #pragma unroll
            for (int r = 0; r < 4; ++r) {
                float v = acc[i][j][r] + bias;
                v = v > 0.f ? v : 0.f;
                Acat[(size_t)(lm0 + r) * 512 + gn] = f2bf(v);
            }
        }
    }
}

// ---------------------------------------------------------------------------
// fused GRU: block = 128 rows x 64 h-cols; waves 2x2, wave = 64x32x3gates.
// A: kk<8 from Acat (emb, bf16, async src-swizzled); kk>=8 from ht fp32 staged
//    in-kernel (reg->cvt->swizzled ds_write) - k_cvt_ht kernel removed.
// B: wrz/wnn LDS-staged async. R2-verified sync: one __syncthreads per K-step.
__global__ __launch_bounds__(256, 2) void k_gru(const ushort_t* __restrict__ Acat,
                                                const float* __restrict__ ht,
                                                const ushort_t* __restrict__ wrz,
                                                const ushort_t* __restrict__ wnn,
                                                const float* __restrict__ bih,
                                                const float* __restrict__ bhh,
                                                float* __restrict__ out,
                                                int base) {
    __shared__ short As[2][128 * 64];                // 32 KiB
    __shared__ short Bs[2][3 * 64 * 64];             // 48 KiB  (80 KiB -> 2 blk/CU)

    const int tid = threadIdx.x;
    const int b = blockIdx.x;
    const int total = gridDim.x;                     // 8*nrb, multiple of 8
    const int lg = (b & 7) * (total >> 3) + (b >> 3);
    const int hb = lg & 7, rb = lg >> 3;
    const int lrow0 = rb * 128;
    const int row0g = base + lrow0;
    const int h0 = hb * 64;
    const int wave = tid >> 6, lane = tid & 63;
    const int wm = wave & 1, wn = wave >> 1;
    const int quad = lane >> 4, l15 = lane & 15;
    const int mb = wm * 64, nb = wn * 32;
    const int srow = lane >> 3, sc8 = lane & 7;
    const int swz = (l15 & 7) << 3;                  // read-side XOR (shorts)

    f32x4 accR[4][2], accZ[4][2], accNI[4][2], accNH[4][2];
    #pragma unroll
    for (int i = 0; i < 4; ++i)
        #pragma unroll
        for (int j = 0; j < 2; ++j) {
            accR[i][j] = (f32x4){0.f, 0.f, 0.f, 0.f};
            accZ[i][j] = (f32x4){0.f, 0.f, 0.f, 0.f};
            accNI[i][j] = (f32x4){0.f, 0.f, 0.f, 0.f};
            accNH[i][j] = (f32x4){0.f, 0.f, 0.f, 0.f};
        }

    const ushort_t* Wr = wrz + (size_t)h0 * 1024;
    const ushort_t* Wz = wrz + (size_t)(512 + h0) * 1024;
    const ushort_t* Wn = wnn + (size_t)h0 * 1024;

    auto stage = [&](int kk, int buf) {
        // A: kk<8 emb half from Acat (async); kk>=8 ht fp32 reg-staged
        if (kk < 8) {
            #pragma unroll
            for (int p = 0; p < 4; ++p) {
                int row = p * 32 + wave * 8 + srow;
                async16(Acat + (size_t)(lrow0 + row) * 512 + kk * 64 + (sc8 ^ srow) * 8,
                        &As[buf][p * 2048 + wave * 512]);
            }
        } else {
            const float* srcb = ht + (size_t)row0g * HW + (kk - 8) * 64;
            #pragma unroll
            for (int p = 0; p < 8; ++p) {
                int idx = p * 256 + tid;
                int row = idx >> 4, c4 = idx & 15;
                float4 v = *(const float4*)(srcb + (size_t)row * HW + c4 * 4);
                ushort_t* d = (ushort_t*)&As[buf][row * 64 + ((c4 * 4) ^ ((row & 7) << 3))];
                d[0] = f2bf(v.x); d[1] = f2bf(v.y); d[2] = f2bf(v.z); d[3] = f2bf(v.w);
            }
        }
        // B: three 64x64 tiles (r, z, n-part) - async, src-swizzled
        #pragma unroll
        for (int p = 0; p < 2; ++p) {
            int row = p * 32 + wave * 8 + srow;
            int goff = row * 1024 + kk * 64 + (sc8 ^ srow) * 8;
            int loff = p * 2048 + wave * 512;
            async16(Wr + goff, &Bs[buf][loff]);
            async16(Wz + goff, &Bs[buf][4096 + loff]);
            async16(Wn + goff, &Bs[buf][8192 + loff]);
        }
    };

    auto compute = [&](int buf, f32x4 (&accN)[4][2]) {
        __builtin_amdgcn_s_setprio(1);
        #pragma unroll
        for (int ks = 0; ks < 2; ++ks) {
            const int kb = (ks * 32 + quad * 8) ^ swz;
            bf16x8 af[4];
            #pragma unroll
            for (int i = 0; i < 4; ++i)
                af[i] = *(const bf16x8*)(&As[buf][(mb + i * 16 + l15) * 64 + kb]);

            bf16x8 br0 = *(const bf16x8*)(&Bs[buf][(nb + l15) * 64 + kb]);
            bf16x8 br1 = *(const bf16x8*)(&Bs[buf][(nb + 16 + l15) * 64 + kb]);
            #pragma unroll
            for (int i = 0; i < 4; ++i) {
                accR[i][0] = __builtin_amdgcn_mfma_f32_16x16x32_bf16(af[i], br0, accR[i][0], 0, 0, 0);
                accR[i][1] = __builtin_amdgcn_mfma_f32_16x16x32_bf16(af[i], br1, accR[i][1], 0, 0, 0);
            }
            bf16x8 bz0 = *(const bf16x8*)(&Bs[buf][4096 + (nb + l15) * 64 + kb]);
            bf16x8 bz1 = *(const bf16x8*)(&Bs[buf][4096 + (nb + 16 + l15) * 64 + kb]);
            #pragma unroll
            for (int i = 0; i < 4; ++i) {
                accZ[i][0] = __builtin_amdgcn_mfma_f32_16x16x32_bf16(af[i], bz0, accZ[i][0], 0, 0, 0);
                accZ[i][1] = __builtin_amdgcn_mfma_f32_16x16x32_bf16(af[i], bz1, accZ[i][1], 0, 0, 0);
            }
            bf16x8 bn0 = *(const bf16x8*)(&Bs[buf][8192 + (nb + l15) * 64 + kb]);
            bf16x8 bn1 = *(const bf16x8*)(&Bs[buf][8192 + (nb + 16 + l15) * 64 + kb]);
            #pragma unroll
            for (int i = 0; i < 4; ++i) {
                accN[i][0] = __builtin_amdgcn_mfma_f32_16x16x32_bf16(af[i], bn0, accN[i][0], 0, 0, 0);
                accN[i][1] = __builtin_amdgcn_mfma_f32_16x16x32_bf16(af[i], bn1, accN[i][1], 0, 0, 0);
            }
        }
        __builtin_amdgcn_s_setprio(0);
    };

    stage(0, 0);
    __syncthreads();
    for (int kk = 0; kk < 8; ++kk) {
        int buf = kk & 1;
        stage(kk + 1, buf ^ 1);              // kk+1 <= 8, always valid
        compute(buf, accNI);
        __syncthreads();
    }
    for (int kk = 8; kk < 16; ++kk) {
        int buf = kk & 1;
        if (kk < 15) stage(kk + 1, buf ^ 1);
        compute(buf, accNH);
        __syncthreads();
    }

    // epilogue
    #pragma unroll
    for (int j = 0; j < 2; ++j) {
        int gn = h0 + nb + j * 16 + l15;
        float br = bih[gn] + bhh[gn];
        float bz = bih[gn + 512] + bhh[gn + 512];
        float bin = bih[gn + 1024], bhn = bhh[gn + 1024];
        #pragma unroll
        for (int i = 0; i < 4; ++i) {
            int gm0 = row0g + mb + i * 16 + quad * 4;
            #pragma unroll
            for (int r = 0; r < 4; ++r) {
                int gm = gm0 + r;
                float rg = 1.f / (1.f + __expf(-(accR[i][j][r] + br)));
                float zg = 1.f / (1.f + __expf(-(accZ[i][j][r] + bz)));
                float ng = tanhf(accNI[i][j][r] + bin + rg * (accNH[i][j][r] + bhn));
                float hp = ht[(size_t)gm * HW + gn];
                out[(size_t)gm * HW + gn] = (1.f - zg) * ng + zg * hp;
            }
        }
    }
}

// ---------------------------------------------------------------------------
extern "C" void kernel_launch(void* const* d_in, const int* in_sizes, int n_in,
                              void* d_out, int out_size, void* d_ws, size_t ws_size,
                              hipStream_t stream) {
    const float* traj   = (const float*)d_in[0];
    const float* neigh  = (const float*)d_in[1];
    const float* dist   = (const float*)d_in[2];
    const float* ht     = (const float*)d_in[3];
    const float* W_emb  = (const float*)d_in[4];
    const float* b_emb  = (const float*)d_in[5];
    const float* w_ih   = (const float*)d_in[6];
    const float* w_hh   = (const float*)d_in[7];
    const float* b_ih   = (const float*)d_in[8];
    const float* b_hh   = (const float*)d_in[9];
    const int*   starts = (const int*)d_in[10];

    // ws layout (all 16B-aligned)
    char* ws = (char*)d_ws;
    int*      sid     = (int*)ws;                         // 262144
    ushort_t* wembT   = (ushort_t*)(ws + 262144);         // 851968
    ushort_t* wrz     = (ushort_t*)(ws + 1114112);        // 2097152
    ushort_t* wnn     = (ushort_t*)(ws + 3211264);        // 1048576
    ushort_t* trajbf  = (ushort_t*)(ws + 4259840);        // 4194304
    ushort_t* Acat    = (ushort_t*)(ws + 8454144);        // chunk_rows * 1024 B

    float* out = (float*)d_out;

    // adaptive chunk size from available workspace (deterministic per call)
    long long avail = (long long)ws_size - 8454144LL;
    int chunk_rows = (int)(avail / 1024);
    chunk_rows &= ~255;                     // multiple of 256 so grids are %8==0
    if (chunk_rows > NTOT) chunk_rows = NTOT;
    if (chunk_rows < 256) chunk_rows = 256;

    k_sid<<<dim3(NTOT / 256), dim3(256), 0, stream>>>(starts, sid);
    k_cvt4<<<dim3(BSAMP * HW / 1024), dim3(256), 0, stream>>>(traj, trajbf, BSAMP * HW / 4);
    k_transpose<<<dim3((HW * EMB_IN + 255) / 256), dim3(256), 0, stream>>>(W_emb, wembT);
    k_build_wrz<<<dim3(1024 * 1024 / 256), dim3(256), 0, stream>>>(w_ih, w_hh, wrz);
    k_build_wnn<<<dim3(512 * 1024 / 256), dim3(256), 0, stream>>>(w_ih, w_hh, wnn);

    for (int base = 0; base < NTOT; base += chunk_rows) {
        int rows = NTOT - base;
        if (rows > chunk_rows) rows = chunk_rows;
        k_emb<<<dim3(4 * (rows / 128)), dim3(256), 0, stream>>>(neigh, trajbf, dist, wembT,
                                                                b_emb, sid, Acat, base);
        k_gru<<<dim3(8 * (rows / 128)), dim3(256), 0, stream>>>(Acat, ht, wrz, wnn,
                                                                b_ih, b_hh, out, base);
    }
}